// Round 3
// baseline (25.262 us; speedup 1.0000x reference)
//
#include <hip/hip_runtime.h>

// STFT -> mag/phase recombine -> ISTFT with pinv basis + window-sum
// normalization is algebraically the IDENTITY on the input samples:
//   - mag*cos(atan2(im,re)) == re, mag*sin(atan2(im,re)) == im
//   - fb (1026x1024 stacked Re/Im DFT rows) has full column rank 1024,
//     so pinv(fb)@fb == I; per-frame recon = win^2 * frame / scale
//   - OLA / window_sumsquare * scale == x_pad; crop undoes reflect-pad.
// Verified round 1: passed, absmax 1.6e-2 << 1.08e-1 threshold.
//
// Round 3: copy tuning. Round-2's f4x2 used i=2t,2t+1 -> 32 B inter-lane
// stride per load instruction (half-utilized cache lines per transaction).
// Fix: split-offset pattern t, t+T, t+2T, t+3T so EVERY load instruction is
// unit-stride across lanes (64x16 B = 1 KB coalesced), 4 independent
// in-flight loads/lane, exact-cover grid (3750 blocks), no loop.

__global__ void identity_copy_f4x4(const float4* __restrict__ in,
                                   float4* __restrict__ out, int T) {
    int t = blockIdx.x * blockDim.x + threadIdx.x;
    if (t < T) {
        float4 a = in[t];
        float4 b = in[t + T];
        float4 c = in[t + 2 * T];
        float4 d = in[t + 3 * T];
        out[t]         = a;
        out[t + T]     = b;
        out[t + 2 * T] = c;
        out[t + 3 * T] = d;
    }
}

__global__ void identity_copy_tail(const float* __restrict__ in,
                                   float* __restrict__ out, int start, int n) {
    int i = start + blockIdx.x * blockDim.x + threadIdx.x;
    if (i < n) out[i] = in[i];
}

extern "C" void kernel_launch(void* const* d_in, const int* in_sizes, int n_in,
                              void* d_out, int out_size, void* d_ws, size_t ws_size,
                              hipStream_t stream) {
    const float* x = (const float*)d_in[0];   // input_data: (32, 480000) fp32
    float* out = (float*)d_out;               // (32, 480000) fp32

    int n4 = out_size >> 2;                   // 3,840,000 float4s
    int T = n4 >> 2;                          // 960,000 threads, 4 float4s each
    int block = 256;
    int grid = (T + block - 1) / block;       // 3750 blocks
    identity_copy_f4x4<<<grid, block, 0, stream>>>(
        (const float4*)x, (float4*)out, T);

    int tail_start = (T << 2) << 2;           // floats covered by f4x4
    int tail = out_size - tail_start;         // 0 for this shape, but be safe
    if (tail > 0) {
        int tgrid = (tail + 63) / 64;
        identity_copy_tail<<<tgrid, 64, 0, stream>>>(x, out, tail_start, out_size);
    }
}

// Round 4
// 22.826 us; speedup vs baseline: 1.1068x; 1.1068x over previous
//
#include <hip/hip_runtime.h>

// STFT -> mag/phase recombine -> ISTFT with pinv basis + window-sum
// normalization is algebraically the IDENTITY on the input samples:
//   - mag*cos(atan2(im,re)) == re, mag*sin(atan2(im,re)) == im
//   - fb (1026x1024 stacked Re/Im DFT rows) has full column rank 1024,
//     so pinv(fb)@fb == I; per-frame recon = win^2 * frame / scale
//   - OLA / window_sumsquare * scale == x_pad; crop undoes reflect-pad.
// Verified rounds 1-3: passed, absmax 1.6e-2 << 1.08e-1 threshold.
//
// Round 4: three hand-rolled copy variants all plateau at 24.3-25.3 us
// (floor: 122.9 MB / 6.29 TB/s = 19.5 us + launch/ramp). Last lever:
// the runtime's own D2D copy path via hipMemcpyAsync (harness-endorsed
// under graph capture) - becomes a graph memcpy node / tuned blit kernel.

extern "C" void kernel_launch(void* const* d_in, const int* in_sizes, int n_in,
                              void* d_out, int out_size, void* d_ws, size_t ws_size,
                              hipStream_t stream) {
    const void* x = d_in[0];                  // input_data: (32, 480000) fp32
    size_t bytes = (size_t)out_size * sizeof(float);   // 61,440,000 B
    hipMemcpyAsync(d_out, x, bytes, hipMemcpyDeviceToDevice, stream);
}